// Round 7
// baseline (418.516 us; speedup 1.0000x reference)
//
#include <hip/hip_runtime.h>
#include <hip/hip_bf16.h>
#include <stdint.h>

typedef unsigned short u16;
typedef unsigned int u32;
typedef unsigned long long u64;
typedef __bf16 bf16x8 __attribute__((ext_vector_type(8)));
typedef _Float16 f16x8 __attribute__((ext_vector_type(8)));
typedef float f32x4 __attribute__((ext_vector_type(4)));

#define M_ROWS 32768   // bs*seq
#define DIM    1024    // inp_dim
#define NPROJ  64
#define NBINS  20
#define FDIM   1280    // NPROJ*NBINS
#define EDIM   1024    // emb_dim

// round-to-nearest-even f32 -> bf16 (no NaNs in this problem)
__device__ __forceinline__ u16 f2bf(float f) {
    union { float f; u32 u; } v; v.f = f;
    return (u16)((v.u + 0x7FFFu + ((v.u >> 16) & 1u)) >> 16);
}

__device__ __forceinline__ float wave_sum(float v) {
    #pragma unroll
    for (int o = 32; o > 0; o >>= 1) v += __shfl_down(v, o, 64);
    return v;
}

__device__ __forceinline__ void gl_lds16(const void* g, void* l) {
    __builtin_amdgcn_global_load_lds(
        (const __attribute__((address_space(1))) void*)g,
        (__attribute__((address_space(3))) void*)l, 16, 0, 0);
}

__device__ __forceinline__ f32x4 mfma16(f16x8 a, f16x8 b, f32x4 c) {
    return __builtin_amdgcn_mfma_f32_16x16x32_f16(a, b, c, 0, 0, 0);
}

// scaled f16 split from two float4s: f = hi + lo*2^-12, lo in normal f16 range
__device__ __forceinline__ void split44(float4 a, float4 b, f16x8& hi, f16x8& lo) {
    float f[8] = {a.x, a.y, a.z, a.w, b.x, b.y, b.z, b.w};
    #pragma unroll
    for (int e = 0; e < 8; e++) {
        _Float16 h = (_Float16)f[e];
        hi[e] = h;
        lo[e] = (_Float16)((f[e] - (float)h) * 4096.0f);
    }
}

// ---------------------------------------------------------------------------
// K1 (unchanged): normalize proj_weight rows, split f16 hi / scaled-lo, store
// LANE-MAJOR fragment images: img[(s*8 + ks*4 + jf)*512 + lane*8 + e] (u16),
// lane = q*16 + m16, proj P = jf*16+m16, k = s*64 + ks*32 + q*8 + e.
__global__ void k_norm_w(const float* __restrict__ w, u16* __restrict__ wswh,
                         u16* __restrict__ wswl) {
    int P = blockIdx.x;
    int t = threadIdx.x;
    float4 v = ((const float4*)(w + (size_t)P * DIM))[t];
    float ss = v.x*v.x + v.y*v.y + v.z*v.z + v.w*v.w;
    ss = wave_sum(ss);
    __shared__ float red[4];
    if ((t & 63) == 0) red[t >> 6] = ss;
    __syncthreads();
    float rn = 1.0f / fmaxf(sqrtf(red[0] + red[1] + red[2] + red[3]), 1e-12f);
    float wn[4] = {v.x*rn, v.y*rn, v.z*rn, v.w*rn};
    u64 hp = 0, lp = 0;
    #pragma unroll
    for (int e = 0; e < 4; e++) {
        _Float16 h = (_Float16)wn[e];
        _Float16 l = (_Float16)((wn[e] - (float)h) * 4096.0f);
        union { _Float16 f; u16 u; } ch, cl;
        ch.f = h; cl.f = l;
        hp |= (u64)ch.u << (16 * e);
        lp |= (u64)cl.u << (16 * e);
    }
    int k0 = 4 * t;
    int s  = k0 >> 6, ks = (k0 >> 5) & 1, q = (k0 >> 3) & 3, e0 = k0 & 7;
    int lane = q * 16 + (P & 15);
    int jf = P >> 4;
    int idx = (s * 8 + ks * 4 + jf) * 512 + lane * 8 + e0;   // u16 units
    *(u64*)(wswh + idx) = hp;
    *(u64*)(wswl + idx) = lp;
}

// ---------------------------------------------------------------------------
// K3: emb_weight fp32 -> bf16, same [EDIM][FDIM] layout. 1280 blocks.
__global__ void k_cvt(const float* __restrict__ s, u16* __restrict__ d) {
    int i = blockIdx.x * 256 + threadIdx.x;
    float4 v = ((const float4*)s)[i];
    ushort4 o; o.x = f2bf(v.x); o.y = f2bf(v.y); o.z = f2bf(v.z); o.w = f2bf(v.w);
    ((ushort4*)d)[i] = o;
}

// ---------------------------------------------------------------------------
// K_FUSED v4 (resubmit — R6 was an infra failure, no data): SPLIT-K x2 for
// TLP (R5 lesson: 2 waves/SIMD grid cap was the stall root cause; both
// LDS-staged and global-B K-loops were ~80% latency-bound). Block = 32 rows,
// 4 waves: wave = wr + 2*kh; waves (wr,kh=0/1) compute the same 16 rows over
// K-halves [0,512)/[512,1024). 1024 blocks -> 4 blocks/CU = 16 waves/CU =
// 4/SIMD. K-loop = v3's barrier-free global-B dataflow (verified R5), 8
// steps. Combine via LDS (+2 syncthreads), act shared by all 4 waves.
__global__ __launch_bounds__(256, 4) void k_fused(const float* __restrict__ x,
        const u16* __restrict__ wswh, const u16* __restrict__ wswl,
        const float* __restrict__ mean, u16* __restrict__ z) {
    __shared__ float mlds[64 * 21];     // means, stride 21
    __shared__ float xch[2][64][33];    // kh=1 -> kh=0 exchange: 32 acc + ssl
    __shared__ float pl[32][65];        // p tile for act redistribution
    int t = threadIdx.x;
    int lane = t & 63, wave = t >> 6;
    int m16 = lane & 15, q = lane >> 4;
    int wr = wave & 1, kh = wave >> 1;
    int bm = blockIdx.x * 32;
    const float* xr = x + (size_t)(bm + wr * 16 + m16) * DIM + kh * 512;

    // stage means (consumed after the barriers below)
    for (int i = t; i < 64 * 21; i += 256) {
        int j = i / 21, b = i - j * 21;
        if (b < 20) mlds[i] = mean[j * 20 + b];
    }

    f32x4 accA[4], accB[4];
    #pragma unroll
    for (int j = 0; j < 4; j++) { accA[j] = (f32x4){0,0,0,0}; accB[j] = (f32x4){0,0,0,0}; }
    float ssl = 0.f;

    // x(0) prefetch
    float4 c0 = *(const float4*)(xr + q * 8);
    float4 c1 = *(const float4*)(xr + q * 8 + 4);
    float4 c2 = *(const float4*)(xr + q * 8 + 32);
    float4 c3 = *(const float4*)(xr + q * 8 + 36);

    const u16* whb = wswh + (size_t)kh * 32768 + lane * 8;
    const u16* wlb = wswl + (size_t)kh * 32768 + lane * 8;

    #pragma unroll
    for (int ss = 0; ss < 8; ss++) {
        float4 n0, n1, n2, n3;
        if (ss < 7) {
            const float* xn = xr + (ss + 1) * 64 + q * 8;
            n0 = *(const float4*)(xn);
            n1 = *(const float4*)(xn + 4);
            n2 = *(const float4*)(xn + 32);
            n3 = *(const float4*)(xn + 36);
        }

        ssl += c0.x*c0.x + c0.y*c0.y + c0.z*c0.z + c0.w*c0.w;
        ssl += c1.x*c1.x + c1.y*c1.y + c1.z*c1.z + c1.w*c1.w;
        ssl += c2.x*c2.x + c2.y*c2.y + c2.z*c2.z + c2.w*c2.w;
        ssl += c3.x*c3.x + c3.y*c3.y + c3.z*c3.z + c3.w*c3.w;

        f16x8 ah0, al0, ah1, al1;
        split44(c0, c1, ah0, al0);
        split44(c2, c3, ah1, al1);

        #pragma unroll
        for (int ks = 0; ks < 2; ks++) {
            f16x8 ah = ks ? ah1 : ah0;
            f16x8 al = ks ? al1 : al0;
            #pragma unroll
            for (int j = 0; j < 4; j++) {
                int fo = (ss * 8 + ks * 4 + j) * 512;    // u16 units
                f16x8 bh = *(const f16x8*)(whb + fo);    // coalesced 16B/lane, L2-hit
                f16x8 bl = *(const f16x8*)(wlb + fo);
                accA[j] = mfma16(ah, bh, accA[j]);
                accB[j] = mfma16(ah, bl, accB[j]);
                accB[j] = mfma16(al, bh, accB[j]);
            }
        }
        c0 = n0; c1 = n1; c2 = n2; c3 = n3;
    }

    // --- split-K combine: kh=1 publishes, kh=0 reduces
    if (kh == 1) {
        #pragma unroll
        for (int j = 0; j < 4; j++)
            #pragma unroll
            for (int r = 0; r < 4; r++) {
                xch[wr][lane][j * 4 + r]      = accA[j][r];
                xch[wr][lane][16 + j * 4 + r] = accB[j][r];
            }
        xch[wr][lane][32] = ssl;
    }
    __syncthreads();
    if (kh == 0) {
        #pragma unroll
        for (int j = 0; j < 4; j++)
            #pragma unroll
            for (int r = 0; r < 4; r++) {
                accA[j][r] += xch[wr][lane][j * 4 + r];
                accB[j][r] += xch[wr][lane][16 + j * 4 + r];
            }
        ssl += xch[wr][lane][32];
        // rn: 4 q-lanes of a row hold disjoint partials
        ssl += __shfl_xor(ssl, 16, 64);
        ssl += __shfl_xor(ssl, 32, 64);
        float rn_own = 1.0f / fmaxf(sqrtf(ssl), 1e-12f);   // for row wr*16+m16
        float rnr[4];
        #pragma unroll
        for (int r = 0; r < 4; r++) rnr[r] = __shfl(rn_own, q * 4 + r, 64);
        // p -> pl  (C layout: row q*4+r, col m16)
        #pragma unroll
        for (int r = 0; r < 4; r++)
            #pragma unroll
            for (int j = 0; j < 4; j++)
                pl[wr * 16 + q * 4 + r][j * 16 + m16] =
                    (accA[j][r] + accB[j][r] * 2.44140625e-4f) * rnr[r];
    }
    __syncthreads();

    // --- act, shared by all 4 waves: thread owns projs 4c..4c+3 of rows
    // rt, rt+16 -> contiguous 160B z chunks
    int c = t & 15;
    int rt = t >> 4;
    #pragma unroll 1
    for (int it = 0; it < 2; it++) {
        int row = rt + 16 * it;
        const float* prow = &pl[row][c * 4];
        float pp[4] = {prow[0], prow[1], prow[2], prow[3]};
        u32 packed[40];
        #pragma unroll
        for (int jj = 0; jj < 4; jj++) {
            float pv = pp[jj];
            const float* mj = &mlds[(c * 4 + jj) * 21];
            float act[NBINS];
            float top0 = -1e30f, top1 = -1e30f, top2 = -1e30f, top3 = -1e30f;
            #pragma unroll
            for (int b = 0; b < NBINS; b++) {
                float d = pv - mj[b];
                float a = __expf(-50.0f * d * d);   // 0.5/sigma2 = 50
                act[b] = a;
                if (a > top3) {
                    if (a > top0)      { top3 = top2; top2 = top1; top1 = top0; top0 = a; }
                    else if (a > top1) { top3 = top2; top2 = top1; top1 = a; }
                    else if (a > top2) { top3 = top2; top2 = a; }
                    else               { top3 = a; }
                }
            }
            float ss = 0.f;
            #pragma unroll
            for (int b = 0; b < NBINS; b++) {
                float a = (act[b] >= top3) ? act[b] : 0.0f;   // keep ties
                act[b] = a;
                ss += a * a;
            }
            float rr = 1.0f / fmaxf(sqrtf(ss), 1e-12f);
            #pragma unroll
            for (int i2 = 0; i2 < 10; i2++) {
                u32 lo = f2bf(act[2 * i2]     * rr);
                u32 hi = f2bf(act[2 * i2 + 1] * rr);
                packed[jj * 10 + i2] = lo | (hi << 16);
            }
        }
        uint4* zp = (uint4*)(z + ((size_t)(bm + row) * FDIM + c * 80));
        #pragma unroll
        for (int u2 = 0; u2 < 10; u2++)
            zp[u2] = make_uint4(packed[4*u2], packed[4*u2+1], packed[4*u2+2], packed[4*u2+3]);
    }
}

// ---------------------------------------------------------------------------
// K6 v3 (unchanged): GEMM2 bf16 MFMA, BK=64 single-buffer 2-barrier,
// G21 both-sides granule swizzle (conflict-free), XCD-swizzled grid.
__global__ __launch_bounds__(256) void k_gemm2(const u16* __restrict__ A,
                                               const u16* __restrict__ B,
                                               float* __restrict__ C) {
    const int K = FDIM, N = EDIM;
    __shared__ u16 As[128 * 64];   // 16KB, [row][64k] granule-swizzled
    __shared__ u16 Bs[128 * 64];   // 16KB
    int t = threadIdx.x;
    int lane = t & 63, wave = t >> 6;
    int sfl  = (blockIdx.y << 3) | blockIdx.x;        // hw dispatch order (x fastest)
    int tile = ((sfl & 7) << 8) | (sfl >> 3);         // xcd*256 + idx-in-xcd
    int bm = (tile >> 3) * 128;                       // 0..255 M-tiles
    int bn = (tile & 7) * 128;                        // 0..7   N-tiles
    int wm = (wave >> 1) * 64, wn = (wave & 1) * 64;
    int m16 = lane & 15, q = lane >> 4;

    f32x4 zero = {0.f, 0.f, 0.f, 0.f};
    f32x4 acc[4][4];
    #pragma unroll
    for (int i = 0; i < 4; i++)
        #pragma unroll
        for (int j = 0; j < 4; j++) acc[i][j] = zero;

    int srow = t >> 3;                  // 0..31
    int gsw  = (t & 7) ^ (srow & 7);    // swizzled source granule
    const u16* gA = A + (size_t)(bm + srow) * K + gsw * 8;
    const u16* gB = B + (size_t)(bn + srow) * K + gsw * 8;
    u16* la = &As[t * 8];
    u16* lb = &Bs[t * 8];

    int swz = (m16 & 7) << 3;

    for (int tt = 0; tt < 20; tt++) {
        int k0 = tt * 64;
        #pragma unroll
        for (int r = 0; r < 4; r++) {
            gl_lds16(gA + (size_t)(32 * r) * K + k0, la + r * 2048);
            gl_lds16(gB + (size_t)(32 * r) * K + k0, lb + r * 2048);
        }
        __syncthreads();
        #pragma unroll
        for (int ks = 0; ks < 2; ks++) {
            bf16x8 af[4], bfr[4];
            #pragma unroll
            for (int i = 0; i < 4; i++)
                af[i] = *(const bf16x8*)&As[(wm + i * 16 + m16) * 64 + ((ks * 32 + q * 8) ^ swz)];
            #pragma unroll
            for (int j = 0; j < 4; j++)
                bfr[j] = *(const bf16x8*)&Bs[(wn + j * 16 + m16) * 64 + ((ks * 32 + q * 8) ^ swz)];
            #pragma unroll
            for (int i = 0; i < 4; i++)
                #pragma unroll
                for (int j = 0; j < 4; j++)
                    acc[i][j] = __builtin_amdgcn_mfma_f32_16x16x32_bf16(
                        af[i], bfr[j], acc[i][j], 0, 0, 0);
        }
        __syncthreads();
    }

    // C/D layout: col = lane&15, row = q*4 + reg  [m89-verified]
    #pragma unroll
    for (int i = 0; i < 4; i++)
        #pragma unroll
        for (int j = 0; j < 4; j++)
            #pragma unroll
            for (int r = 0; r < 4; r++) {
                int row = bm + wm + i * 16 + q * 4 + r;
                int col = bn + wn + j * 16 + m16;
                C[(size_t)row * N + col] = acc[i][j][r];
            }
}

// ---------------------------------------------------------------------------
extern "C" void kernel_launch(void* const* d_in, const int* in_sizes, int n_in,
                              void* d_out, int out_size, void* d_ws, size_t ws_size,
                              hipStream_t stream) {
    const float* x    = (const float*)d_in[0];   // [32768][1024]
    const float* pw   = (const float*)d_in[1];   // [64][1024]
    const float* mean = (const float*)d_in[2];   // [64][20]
    const float* emb  = (const float*)d_in[3];   // [1024][1280]
    float* out = (float*)d_out;                  // [32768][1024] fp32

    char* ws = (char*)d_ws;
    u16*   z    = (u16*)(ws);                    // 83,886,080 B
    u16*   wswh = (u16*)(ws + 83886080);         //    131,072 B (lane-major frag images)
    u16*   wswl = (u16*)(ws + 84017152);         //    131,072 B
    u16*   embW = (u16*)(ws + 84148224);         //  2,621,440 B
    // total: 86,769,664 B

    k_norm_w<<<64, 256, 0, stream>>>(pw, wswh, wswl);
    k_cvt<<<(EDIM * FDIM / 4) / 256, 256, 0, stream>>>(emb, embW);
    k_fused<<<M_ROWS / 32, 256, 0, stream>>>(x, wswh, wswl, mean, z);
    k_gemm2<<<dim3(EDIM / 128, M_ROWS / 128), 256, 0, stream>>>(z, embW, out);
}